// Round 1
// baseline (2123.794 us; speedup 1.0000x reference)
//
#include <hip/hip_runtime.h>
#include <math.h>

#define BSZ   384
#define BM1   383
#define DIM   256
#define NZTOT 768
#define NBLK  128
#define RPB   3
#define TPB   384
#define NITER 100

// ---- ws layout (float offsets) ----
#define OFF_Z    0          // 768*256 = 196608
#define OFF_NRM  196608     // 768
#define OFF_K    197376     // 384*768 = 294912
#define OFF_B0   492288     // 384*383 = 147072
#define OFF_B1   639360     // 147072
#define OFF_NUM  786432     // 128 floats
#define OFF_DEN  786560     // 128 floats
#define OFF_ARR  786688     // 128 ints
#define OFF_LOSS 786816     // 2 doubles (byte off 3147264, 8B aligned)
// total ~3.15 MB of ws

__device__ __forceinline__ float bcastf(float v, int l) {
    return __int_as_float(__builtin_amdgcn_readlane(__float_as_int(v), l));
}

__global__ void init_kernel(float* num, float* den, int* arr, double* lossAcc) {
    int t = threadIdx.x;
    if (t < 128) { num[t] = 0.f; den[t] = 0.f; arr[t] = 0; }
    if (t < 2) lossAcc[t] = 0.0;
}

__global__ void __launch_bounds__(64)
norm_kernel(const float* __restrict__ xis, const float* __restrict__ xjs,
            float* __restrict__ Z, float* __restrict__ nrm2) {
    const int row  = blockIdx.x;     // 0..767
    const int lane = threadIdx.x;    // 0..63
    const float* src = (row < BSZ) ? (xis + (size_t)row * DIM)
                                   : (xjs + (size_t)(row - BSZ) * DIM);
    float4 x = reinterpret_cast<const float4*>(src)[lane];
    float s = x.x*x.x + x.y*x.y + x.z*x.z + x.w*x.w;
    for (int m = 32; m; m >>= 1) s += __shfl_xor(s, m, 64);
    float nrm = sqrtf(s);
    float4 z;
    z.x = x.x / nrm; z.y = x.y / nrm; z.z = x.z / nrm; z.w = x.w / nrm;
    reinterpret_cast<float4*>(Z + (size_t)row * DIM)[lane] = z;
    float s2 = z.x*z.x + z.y*z.y + z.z*z.z + z.w*z.w;
    for (int m = 32; m; m >>= 1) s2 += __shfl_xor(s2, m, 64);
    if (lane == 0) nrm2[row] = s2;
}

__global__ void __launch_bounds__(256)
k_kernel(const float* __restrict__ Z, const float* __restrict__ nrm2,
         float* __restrict__ Km) {
    const int i = blockIdx.x;                        // 0..383
    const int j = blockIdx.y * 256 + threadIdx.x;    // 0..767
    __shared__ float zi[DIM];
    zi[threadIdx.x] = Z[(size_t)i * DIM + threadIdx.x];
    __syncthreads();
    const float4* zr = reinterpret_cast<const float4*>(Z + (size_t)j * DIM);
    float acc = 0.f;
    #pragma unroll 8
    for (int k = 0; k < DIM/4; ++k) {
        float4 v = zr[k];
        acc = fmaf(zi[4*k+0], v.x, acc);
        acc = fmaf(zi[4*k+1], v.y, acc);
        acc = fmaf(zi[4*k+2], v.z, acc);
        acc = fmaf(zi[4*k+3], v.w, acc);
    }
    float sq = nrm2[i] + nrm2[j] - 2.f * acc;
    sq = fmaxf(sq, 0.f);
    Km[(size_t)i * NZTOT + j] = expf(-0.1f * sq);
}

__global__ void __launch_bounds__(TPB)
pgd_kernel(const float* __restrict__ Km, const float* __restrict__ alpha_init,
           float* __restrict__ b0, float* __restrict__ b1,
           float* num, float* den, int* arr, double* lossAcc,
           float* __restrict__ out) {
    const int g    = blockIdx.x;     // 0..127
    const int tid  = threadIdx.x;    // 0..383
    const int lane = tid & 63;
    const int wv   = tid >> 6;       // 0..5

    __shared__ float  zf[RPB][TPB];   // zfull columns (this block's rows)
    __shared__ float  wsh[RPB][TPB];  // W = KK @ zfull columns
    __shared__ float  Ssh[RPB], Dsh[RPB];
    __shared__ float  rscr[6][8];
    __shared__ double dscr[6][2];
    __shared__ float  relsh;

    const int  i   = tid;
    const bool act = (i < BM1);

    // alpha0 = clip(relu(alpha_init), 0, 1) into both buffers (block-local rows)
    for (int r = 0; r < RPB; ++r) {
        const int b = g * RPB + r;
        if (act) {
            float v = alpha_init[(size_t)b * BM1 + i];
            v = fminf(fmaxf(v, 0.f), 1.f);
            b0[(size_t)b * BM1 + i] = v;
            b1[(size_t)b * BM1 + i] = v;
        }
    }

    float* A = b0;   // current a
    float* P = b1;   // a_prev (a_new written here, then swap)

    for (int t = 0; t < NITER; ++t) {
        const float beta = (float)t / ((float)t + 3.0f);

        // ---- phase 1: z build + S_b, dot_b partials ----
        float sp[RPB], dp[RPB];
        float denp = 0.f;
        for (int r = 0; r < RPB; ++r) {
            const int b = g * RPB + r;
            float s = 0.f, d = 0.f;
            if (act) {
                const float av = A[(size_t)b * BM1 + i];
                const float pv = P[(size_t)b * BM1 + i];
                const float z  = av + beta * (av - pv);
                const int   I  = i + (i >= b);
                zf[r][I] = z;
                s = z;
                d = Km[(size_t)b * NZTOT + I] * z;
                denp += av * av;
            } else {
                zf[r][b] = 0.f;   // diagonal hole (tid==383 only)
            }
            sp[r] = s; dp[r] = d;
        }
        {
            float vv[6] = { sp[0], sp[1], sp[2], dp[0], dp[1], dp[2] };
            #pragma unroll
            for (int k = 0; k < 6; ++k) {
                float x = vv[k];
                x += __shfl_down(x, 32, 64); x += __shfl_down(x, 16, 64);
                x += __shfl_down(x,  8, 64); x += __shfl_down(x,  4, 64);
                x += __shfl_down(x,  2, 64); x += __shfl_down(x,  1, 64);
                if (lane == 0) rscr[wv][k] = x;
            }
        }
        __syncthreads();
        if (tid < 6) {
            float s = 0.f;
            for (int w = 0; w < 6; ++w) s += rscr[w][tid];
            if (tid < 3) Ssh[tid] = s; else Dsh[tid - 3] = s;
        }
        __syncthreads();

        // ---- phase 2: W[:,r] = KK @ zf[r]  (KK symmetric: read KK[J, i]) ----
        float acc0 = 0.f, acc1 = 0.f, acc2 = 0.f;
        #pragma unroll 1
        for (int J0 = 0; J0 < BSZ; J0 += 64) {
            const float z0 = zf[0][J0 + lane];
            const float z1 = zf[1][J0 + lane];
            const float z2 = zf[2][J0 + lane];
            const float* Kp = Km + (size_t)J0 * NZTOT + i;
            #pragma unroll
            for (int l = 0; l < 64; ++l) {
                const float kk = Kp[(size_t)l * NZTOT];
                acc0 = fmaf(kk, bcastf(z0, l), acc0);
                acc1 = fmaf(kk, bcastf(z1, l), acc1);
                acc2 = fmaf(kk, bcastf(z2, l), acc2);
            }
        }
        wsh[0][tid] = acc0; wsh[1][tid] = acc1; wsh[2][tid] = acc2;
        __syncthreads();

        // ---- phase 3: grad, clipped step, rel partials ----
        float nump = 0.f;
        for (int r = 0; r < RPB; ++r) {
            const int b = g * RPB + r;
            if (act) {
                const int   I  = i + (i >= b);
                const float z  = zf[r][I];
                const float w  = wsh[r][I];
                const float kb = Km[(size_t)b * NZTOT + I];
                const float grad = Ssh[r] * (1.f - kb) + 0.1f * z + w - Dsh[r] - 2.0f;
                const float av = A[(size_t)b * BM1 + i];
                float an = z - 0.001f * grad;
                an = fminf(fmaxf(an, 0.f), 1.f);
                P[(size_t)b * BM1 + i] = an;
                const float dd = an - av;
                nump += dd * dd;
            }
        }
        {
            float x = nump, y = denp;
            x += __shfl_down(x, 32, 64); x += __shfl_down(x, 16, 64);
            x += __shfl_down(x,  8, 64); x += __shfl_down(x,  4, 64);
            x += __shfl_down(x,  2, 64); x += __shfl_down(x,  1, 64);
            y += __shfl_down(y, 32, 64); y += __shfl_down(y, 16, 64);
            y += __shfl_down(y,  8, 64); y += __shfl_down(y,  4, 64);
            y += __shfl_down(y,  2, 64); y += __shfl_down(y,  1, 64);
            if (lane == 0) { rscr[wv][0] = x; rscr[wv][1] = y; }
        }
        __syncthreads();
        if (tid == 0) {
            float nb = 0.f, db = 0.f;
            for (int w = 0; w < 6; ++w) { nb += rscr[w][0]; db += rscr[w][1]; }
            __hip_atomic_fetch_add(&num[t], nb, __ATOMIC_RELAXED, __HIP_MEMORY_SCOPE_AGENT);
            __hip_atomic_fetch_add(&den[t], db, __ATOMIC_RELAXED, __HIP_MEMORY_SCOPE_AGENT);
            __hip_atomic_fetch_add(&arr[t], 1, __ATOMIC_RELEASE, __HIP_MEMORY_SCOPE_AGENT);
            while (__hip_atomic_load(&arr[t], __ATOMIC_ACQUIRE, __HIP_MEMORY_SCOPE_AGENT) < NBLK)
                __builtin_amdgcn_s_sleep(2);
            const float nn = __hip_atomic_load(&num[t], __ATOMIC_RELAXED, __HIP_MEMORY_SCOPE_AGENT);
            const float dd = __hip_atomic_load(&den[t], __ATOMIC_RELAXED, __HIP_MEMORY_SCOPE_AGENT);
            relsh = sqrtf(nn) / (sqrtf(dd) + 1e-8f);
        }
        __syncthreads();
        const float relv = relsh;
        { float* tmp = A; A = P; P = tmp; }   // a <- a_new, a_prev <- a
        __syncthreads();                      // protect LDS reuse next iter
        if (relv < 0.01f) break;              // uniform across all blocks
    }

    // ---- loss phase (fp64 accumulation) ----
    double np = 0.0, pp = 0.0;
    for (int r = 0; r < RPB; ++r) {
        const int b = g * RPB + r;
        if (act) {
            const float ay = A[(size_t)b * BM1 + i];   // already in [0,1]
            const int   I  = i + (i >= b);
            np += (double)ay * (double)Km[(size_t)I * NZTOT + BSZ + b];
            pp += (double)ay * (double)Km[(size_t)b * NZTOT + BSZ + b];
        }
    }
    {
        double x = np, y = pp;
        for (int o = 32; o; o >>= 1) { x += __shfl_down(x, o, 64); y += __shfl_down(y, o, 64); }
        if (lane == 0) { dscr[wv][0] = x; dscr[wv][1] = y; }
    }
    __syncthreads();
    if (tid == 0) {
        double nb = 0.0, pb = 0.0;
        for (int w = 0; w < 6; ++w) { nb += dscr[w][0]; pb += dscr[w][1]; }
        __hip_atomic_fetch_add(&lossAcc[0], nb, __ATOMIC_RELAXED, __HIP_MEMORY_SCOPE_AGENT);
        __hip_atomic_fetch_add(&lossAcc[1], pb, __ATOMIC_RELAXED, __HIP_MEMORY_SCOPE_AGENT);
        __hip_atomic_fetch_add(&arr[NITER], 1, __ATOMIC_RELEASE, __HIP_MEMORY_SCOPE_AGENT);
        if (g == 0) {
            while (__hip_atomic_load(&arr[NITER], __ATOMIC_ACQUIRE, __HIP_MEMORY_SCOPE_AGENT) < NBLK)
                __builtin_amdgcn_s_sleep(2);
            const double nn = __hip_atomic_load(&lossAcc[0], __ATOMIC_RELAXED, __HIP_MEMORY_SCOPE_AGENT);
            const double pv = __hip_atomic_load(&lossAcc[1], __ATOMIC_RELAXED, __HIP_MEMORY_SCOPE_AGENT);
            out[0] = expf((float)(nn / 384.0 - pv / 384.0));
        }
    }
}

extern "C" void kernel_launch(void* const* d_in, const int* in_sizes, int n_in,
                              void* d_out, int out_size, void* d_ws, size_t ws_size,
                              hipStream_t stream) {
    const float* xis        = (const float*)d_in[0];
    const float* xjs        = (const float*)d_in[1];
    const float* alpha_init = (const float*)d_in[2];
    float* ws   = (float*)d_ws;
    float* Z    = ws + OFF_Z;
    float* nrm2 = ws + OFF_NRM;
    float* Km   = ws + OFF_K;
    float* b0   = ws + OFF_B0;
    float* b1   = ws + OFF_B1;
    float* num  = ws + OFF_NUM;
    float* den  = ws + OFF_DEN;
    int*   arr  = (int*)(ws + OFF_ARR);
    double* lossAcc = (double*)(ws + OFF_LOSS);
    float* out  = (float*)d_out;

    hipLaunchKernelGGL(init_kernel, dim3(1), dim3(256), 0, stream, num, den, arr, lossAcc);
    hipLaunchKernelGGL(norm_kernel, dim3(NZTOT), dim3(64), 0, stream, xis, xjs, Z, nrm2);
    hipLaunchKernelGGL(k_kernel, dim3(BSZ, 3), dim3(256), 0, stream, Z, nrm2, Km);
    hipLaunchKernelGGL(pgd_kernel, dim3(NBLK), dim3(TPB), 0, stream,
                       Km, alpha_init, b0, b1, num, den, arr, lossAcc, out);
}